// Round 8
// baseline (108.548 us; speedup 1.0000x reference)
//
#include <hip/hip_runtime.h>
#include <math.h>

// ws layout (fast path): [256, 256+16N): vavb (8 x f16 per vertex);
// [256+16N, +48N): pq (24 x f16 per vertex = Rk^T va | Rk^T vb);
// then part1 (5*nb1a floats), part2 (nb2 floats).
static constexpr int BLOCK = 256;
static constexpr int WAVES = BLOCK / 64;
static constexpr int KVAL = 4;

typedef float f4 __attribute__((ext_vector_type(4)));
typedef int i4 __attribute__((ext_vector_type(4)));
typedef unsigned int u4v __attribute__((ext_vector_type(4)));
union VV { u4v u4; _Float16 h[8]; };
union PQ { u4v u[3]; _Float16 h[24]; };
union F4S { f4 v; float f[4]; };
union F12 { f4 v[3]; float f[12]; };
union F36 { f4 v[9]; float f[36]; };

__device__ __forceinline__ float ntl(const float* p) {
  return __builtin_nontemporal_load(p);
}
__device__ __forceinline__ f4 ntl4(const f4* p) {
  return __builtin_nontemporal_load(p);
}
__device__ __forceinline__ i4 nti4(const i4* p) {
  return __builtin_nontemporal_load(p);
}

__device__ __forceinline__ void norm3(float x, float y, float z,
                                      float& ox, float& oy, float& oz) {
  float inv = 1.0f / (sqrtf(x * x + y * y + z * z) + 1e-12f);
  ox = x * inv; oy = y * inv; oz = z * inv;
}

__device__ __forceinline__ void crossfield(const float* __restrict__ u,
                                           const float* __restrict__ v,
                                           const float* __restrict__ theta,
                                           int n, float va[3], float vb[3]) {
  float s, c;
  __sincosf(theta[n], &s, &c);
  float ux = u[3 * n], uy = u[3 * n + 1], uz = u[3 * n + 2];
  float vx = v[3 * n], vy = v[3 * n + 1], vz = v[3 * n + 2];
  norm3(ux * c + vx * s, uy * c + vy * s, uz * c + vz * s, va[0], va[1], va[2]);
  norm3(vx * c - ux * s, vy * c - uy * s, vz * c - uz * s, vb[0], vb[1], vb[2]);
}

template <int NV>
__device__ __forceinline__ void block_reduce(float (&p)[NV]) {
#pragma unroll
  for (int off = 32; off > 0; off >>= 1)
#pragma unroll
    for (int q = 0; q < NV; ++q) p[q] += __shfl_down(p[q], off, 64);
  __shared__ float sm[WAVES][NV];
  int wave = threadIdx.x >> 6, lane = threadIdx.x & 63;
  if (lane == 0)
#pragma unroll
    for (int q = 0; q < NV; ++q) sm[wave][q] = p[q];
  __syncthreads();
  if (threadIdx.x == 0) {
#pragma unroll
    for (int q = 0; q < NV; ++q) {
      float t = 0.f;
#pragma unroll
      for (int w = 1; w < WAVES; ++w) t += sm[w][q];
      p[q] += t;
    }
  }
}

// per-vertex streaming math; p = {sdf, eik, morse, halign, -}
__device__ __forceinline__ void vmath(float mpv, float gx, float gy, float gz,
                                      const float* h, float n0, float n1, float n2,
                                      float th, float ux, float uy, float uz,
                                      float vx, float vy, float vz,
                                      u4v* __restrict__ vavb, long n, float (&p)[5]) {
  p[0] += fabsf(mpv);
  p[1] += fabsf(sqrtf(gx * gx + gy * gy + gz * gz) - 1.0f);
  p[2] += fabsf(n0 * h[0] + n1 * h[3] + n2 * h[6]) +
          fabsf(n0 * h[1] + n1 * h[4] + n2 * h[7]) +
          fabsf(n0 * h[2] + n1 * h[5] + n2 * h[8]);
  float s, c;
  __sincosf(th, &s, &c);
  float va[3], vb[3];
  norm3(ux * c + vx * s, uy * c + vy * s, uz * c + vz * s, va[0], va[1], va[2]);
  norm3(vx * c - ux * s, vy * c - uy * s, vz * c - uz * s, vb[0], vb[1], vb[2]);
  {
    float a0 = va[0] * h[0] + va[1] * h[3] + va[2] * h[6];
    float a1 = va[0] * h[1] + va[1] * h[4] + va[2] * h[7];
    float a2 = va[0] * h[2] + va[1] * h[5] + va[2] * h[8];
    float b0 = vb[0] * h[0] + vb[1] * h[3] + vb[2] * h[6];
    float b1 = vb[0] * h[1] + vb[1] * h[4] + vb[2] * h[7];
    float b2 = vb[0] * h[2] + vb[1] * h[5] + vb[2] * h[8];
    p[3] += fabsf(a1 * va[2] - a2 * va[1]) + fabsf(a2 * va[0] - a0 * va[2]) +
            fabsf(a0 * va[1] - a1 * va[0]) + fabsf(b1 * vb[2] - b2 * vb[1]) +
            fabsf(b2 * vb[0] - b0 * vb[2]) + fabsf(b0 * vb[1] - b1 * vb[0]);
  }
  VV w;
  w.h[0] = (_Float16)va[0]; w.h[1] = (_Float16)va[1]; w.h[2] = (_Float16)va[2];
  w.h[3] = (_Float16)vb[0]; w.h[4] = (_Float16)vb[1]; w.h[5] = (_Float16)vb[2];
  w.h[6] = (_Float16)0.f;   w.h[7] = (_Float16)0.f;
  vavb[n] = w.u4;
}

// ---- pass 1a: small streams, VPT=4, all loads upfront ----------------------
__global__ __launch_bounds__(BLOCK) void pass1a_kernel(
    const float* __restrict__ theta, const float* __restrict__ u,
    const float* __restrict__ v, u4v* __restrict__ vavb, int N,
    const float* __restrict__ pred, const float* __restrict__ pgrad,
    const float* __restrict__ mp, const float* __restrict__ grad,
    const float* __restrict__ H, const float* __restrict__ ngt,
    float* __restrict__ part1, int nb1, int M) {
  long base = 4L * (blockIdx.x * (long)BLOCK + threadIdx.x);
  float p[5] = {0.f, 0.f, 0.f, 0.f, 0.f};  // sdf, eik, morse, halign, inter
  if (base + 3 < M) {
    F4S pr; pr.v = ntl4((const f4*)(pred + base));
    F12 pg;
#pragma unroll
    for (int q = 0; q < 3; ++q) pg.v[q] = ntl4((const f4*)(pgrad + 3 * base) + q);
#pragma unroll
    for (int k = 0; k < 4; ++k) {
      p[4] += __expf(-100.0f * fabsf(pr.f[k]));
      float gx = pg.f[3 * k], gy = pg.f[3 * k + 1], gz = pg.f[3 * k + 2];
      p[1] += fabsf(sqrtf(gx * gx + gy * gy + gz * gz) - 1.0f);
    }
  } else if (base < M) {
    for (int k = 0; k < 4; ++k) {
      long i = base + k;
      if (i < M) {
        p[4] += __expf(-100.0f * fabsf(pred[i]));
        float gx = pgrad[3 * i], gy = pgrad[3 * i + 1], gz = pgrad[3 * i + 2];
        p[1] += fabsf(sqrtf(gx * gx + gy * gy + gz * gz) - 1.0f);
      }
    }
  }
  if (base + 3 < N) {
    F4S mpv; mpv.v = ntl4((const f4*)(mp + base));
    F12 g;
#pragma unroll
    for (int q = 0; q < 3; ++q) g.v[q] = ntl4((const f4*)(grad + 3 * base) + q);
    F36 h;
#pragma unroll
    for (int q = 0; q < 9; ++q) h.v[q] = ntl4((const f4*)(H + 9 * base) + q);
    F12 ng;
#pragma unroll
    for (int q = 0; q < 3; ++q) ng.v[q] = ntl4((const f4*)(ngt + 3 * base) + q);
    F4S th; th.v = ntl4((const f4*)(theta + base));
    F12 uu;
#pragma unroll
    for (int q = 0; q < 3; ++q) uu.v[q] = ntl4((const f4*)(u + 3 * base) + q);
    F12 vv;
#pragma unroll
    for (int q = 0; q < 3; ++q) vv.v[q] = ntl4((const f4*)(v + 3 * base) + q);
#pragma unroll
    for (int k = 0; k < 4; ++k)
      vmath(mpv.f[k], g.f[3 * k], g.f[3 * k + 1], g.f[3 * k + 2], h.f + 9 * k,
            ng.f[3 * k], ng.f[3 * k + 1], ng.f[3 * k + 2], th.f[k],
            uu.f[3 * k], uu.f[3 * k + 1], uu.f[3 * k + 2],
            vv.f[3 * k], vv.f[3 * k + 1], vv.f[3 * k + 2], vavb, base + k, p);
  } else if (base < N) {
    for (int k = 0; k < 4; ++k) {
      long i = base + k;
      if (i < N) {
        float hh[9];
#pragma unroll
        for (int q = 0; q < 9; ++q) hh[q] = H[9 * i + q];
        vmath(mp[i], grad[3 * i], grad[3 * i + 1], grad[3 * i + 2], hh,
              ngt[3 * i], ngt[3 * i + 1], ngt[3 * i + 2], theta[i],
              u[3 * i], u[3 * i + 1], u[3 * i + 2],
              v[3 * i], v[3 * i + 1], v[3 * i + 2], vavb, i, p);
      }
    }
  }
  block_reduce<5>(p);
  if (threadIdx.x == 0) {
#pragma unroll
    for (int q = 0; q < 5; ++q) part1[q * nb1 + blockIdx.x] = p[q];
  }
}

// ---- pass 1b: rot -> pq transform, pure streaming, high MLP ----------------
__global__ __launch_bounds__(BLOCK) void pass1b_kernel(
    const float* __restrict__ rot, const u4v* __restrict__ vavb,
    u4v* __restrict__ pq, int N) {
  int i = blockIdx.x * BLOCK + threadIdx.x;
  if (i >= N) return;
  // issue all 10 loads upfront
  F36 r;
  const f4* rv = (const f4*)(rot + (size_t)i * 36);
#pragma unroll
  for (int q = 0; q < 9; ++q) r.v[q] = ntl4(rv + q);
  VV ws; ws.u4 = vavb[i];
  float va[3] = {(float)ws.h[0], (float)ws.h[1], (float)ws.h[2]};
  float vb[3] = {(float)ws.h[3], (float)ws.h[4], (float)ws.h[5]};
  PQ o;
#pragma unroll
  for (int k = 0; k < KVAL; ++k) {
    const float* R = r.f + 9 * k;
#pragma unroll
    for (int j = 0; j < 3; ++j) {
      float pa = R[j] * va[0] + R[3 + j] * va[1] + R[6 + j] * va[2];
      float pb = R[j] * vb[0] + R[3 + j] * vb[1] + R[6 + j] * vb[2];
      o.h[6 * k + j] = (_Float16)pa;
      o.h[6 * k + 3 + j] = (_Float16)pb;
    }
  }
  u4v* dst = pq + (size_t)i * 3;
  dst[0] = o.u[0]; dst[1] = o.u[1]; dst[2] = o.u[2];
}

// ---- pass 2: neighbor consistency, 8 loads/thread, one epoch ---------------
__global__ __launch_bounds__(BLOCK) void pass2_kernel(
    const u4v* __restrict__ vavb, const u4v* __restrict__ pq,
    const i4* __restrict__ nbr, float* __restrict__ part2, int N) {
  int n = blockIdx.x * BLOCK + threadIdx.x;
  float p[1] = {0.f};
  if (n < N) {
    i4 jj = nti4(nbr + n);
    int js[4] = {jj.x, jj.y, jj.z, jj.w};
    VV wn[4];
#pragma unroll
    for (int k = 0; k < KVAL; ++k) wn[k].u4 = vavb[js[k]];
    PQ o;
    const u4v* src = pq + (size_t)n * 3;
    o.u[0] = src[0]; o.u[1] = src[1]; o.u[2] = src[2];
    float nsum = 0.f;
#pragma unroll
    for (int k = 0; k < KVAL; ++k) {
      float pa0 = (float)o.h[6 * k],     pa1 = (float)o.h[6 * k + 1],
            pa2 = (float)o.h[6 * k + 2];
      float pb0 = (float)o.h[6 * k + 3], pb1 = (float)o.h[6 * k + 4],
            pb2 = (float)o.h[6 * k + 5];
      float aj0 = (float)wn[k].h[0], aj1 = (float)wn[k].h[1], aj2 = (float)wn[k].h[2];
      float bj0 = (float)wn[k].h[3], bj1 = (float)wn[k].h[4], bj2 = (float)wn[k].h[5];
      nsum += fabsf(pa0 * aj0 + pa1 * aj1 + pa2 * aj2) +
              fabsf(pa0 * bj0 + pa1 * bj1 + pa2 * bj2) +
              fabsf(pb0 * aj0 + pb1 * aj1 + pb2 * aj2) +
              fabsf(pb0 * bj0 + pb1 * bj1 + pb2 * bj2) - 2.0f;
    }
    p[0] = nsum;
  }
  block_reduce<1>(p);
  if (threadIdx.x == 0) part2[blockIdx.x] = p[0];
}

// ---- finalize ---------------------------------------------------------------
__global__ __launch_bounds__(BLOCK) void finalize_fast(
    const float* __restrict__ part1, int nb1, const float* __restrict__ part2,
    int nb2, float* __restrict__ out, int N, int M) {
  float s[6] = {0.f, 0.f, 0.f, 0.f, 0.f, 0.f};
  for (int b = threadIdx.x; b < nb1; b += BLOCK) {
#pragma unroll
    for (int q = 0; q < 5; ++q) s[q] += part1[q * nb1 + b];
  }
  for (int b = threadIdx.x; b < nb2; b += BLOCK) s[5] += part2[b];
  block_reduce<6>(s);
  if (threadIdx.x == 0) {
    float sdf = s[0] / (float)N;
    float eik = s[1] / (float)(N + M);
    float morse = 0.5f * s[2] / (3.0f * (float)N);
    float th = 0.5f * s[3] / (3.0f * (float)N);
    float inter = s[4] / (float)M;
    float nb = s[5] / ((float)N * (float)KVAL);
    float loss = 7000.0f * sdf + 600.0f * inter + 50.0f * eik + 3.0f * morse +
                 10.0f * th + 30.0f * nb;
    out[0] = loss; out[1] = sdf; out[2] = inter; out[3] = eik;
    out[4] = morse; out[5] = th; out[6] = nb;
  }
}

// ---------------- fallback path (atomics, no ws tables) ---------------------
__global__ __launch_bounds__(BLOCK) void vertex_kernel(
    const float* __restrict__ mp, const float* __restrict__ grad,
    const float* __restrict__ H, const float* __restrict__ ngt,
    const float* __restrict__ theta, const float* __restrict__ u,
    const float* __restrict__ v, const float* __restrict__ rot,
    const int* __restrict__ nbr, float* __restrict__ acc, int N) {
  int n = blockIdx.x * blockDim.x + threadIdx.x;
  float p[5] = {0.f, 0.f, 0.f, 0.f, 0.f};
  if (n < N) {
    float hh[9];
#pragma unroll
    for (int i = 0; i < 9; ++i) hh[i] = H[9 * (size_t)n + i];
    p[0] = fabsf(mp[n]);
    float gx = grad[3 * n], gy = grad[3 * n + 1], gz = grad[3 * n + 2];
    p[1] = fabsf(sqrtf(gx * gx + gy * gy + gz * gz) - 1.0f);
    float n0 = ngt[3 * n], n1 = ngt[3 * n + 1], n2 = ngt[3 * n + 2];
    p[2] = fabsf(n0 * hh[0] + n1 * hh[3] + n2 * hh[6]) +
           fabsf(n0 * hh[1] + n1 * hh[4] + n2 * hh[7]) +
           fabsf(n0 * hh[2] + n1 * hh[5] + n2 * hh[8]);
    float va[3], vb[3];
    crossfield(u, v, theta, n, va, vb);
    {
      float a0 = va[0] * hh[0] + va[1] * hh[3] + va[2] * hh[6];
      float a1 = va[0] * hh[1] + va[1] * hh[4] + va[2] * hh[7];
      float a2 = va[0] * hh[2] + va[1] * hh[5] + va[2] * hh[8];
      float b0 = vb[0] * hh[0] + vb[1] * hh[3] + vb[2] * hh[6];
      float b1 = vb[0] * hh[1] + vb[1] * hh[4] + vb[2] * hh[7];
      float b2 = vb[0] * hh[2] + vb[1] * hh[5] + vb[2] * hh[8];
      p[3] = fabsf(a1 * va[2] - a2 * va[1]) + fabsf(a2 * va[0] - a0 * va[2]) +
             fabsf(a0 * va[1] - a1 * va[0]) + fabsf(b1 * vb[2] - b2 * vb[1]) +
             fabsf(b2 * vb[0] - b0 * vb[2]) + fabsf(b0 * vb[1] - b1 * vb[0]);
    }
    float nsum = 0.f;
    const float* R = rot + (size_t)n * (KVAL * 9);
#pragma unroll
    for (int k = 0; k < KVAL; ++k) {
      int j = nbr[KVAL * (size_t)n + k];
      float vaj[3], vbj[3];
      crossfield(u, v, theta, j, vaj, vbj);
      float r0 = R[9 * k + 0], r1 = R[9 * k + 1], r2 = R[9 * k + 2];
      float r3 = R[9 * k + 3], r4 = R[9 * k + 4], r5 = R[9 * k + 5];
      float r6 = R[9 * k + 6], r7 = R[9 * k + 7], r8 = R[9 * k + 8];
      float wa0 = r0 * vaj[0] + r1 * vaj[1] + r2 * vaj[2];
      float wa1 = r3 * vaj[0] + r4 * vaj[1] + r5 * vaj[2];
      float wa2 = r6 * vaj[0] + r7 * vaj[1] + r8 * vaj[2];
      float wb0 = r0 * vbj[0] + r1 * vbj[1] + r2 * vbj[2];
      float wb1 = r3 * vbj[0] + r4 * vbj[1] + r5 * vbj[2];
      float wb2 = r6 * vbj[0] + r7 * vbj[1] + r8 * vbj[2];
      nsum += fabsf(va[0] * wa0 + va[1] * wa1 + va[2] * wa2) +
              fabsf(va[0] * wb0 + va[1] * wb1 + va[2] * wb2) +
              fabsf(vb[0] * wa0 + vb[1] * wa1 + vb[2] * wa2) +
              fabsf(vb[0] * wb0 + vb[1] * wb1 + vb[2] * wb2) - 2.0f;
    }
    p[4] = nsum;
  }
  block_reduce<5>(p);
  if (threadIdx.x == 0) {
    atomicAdd(&acc[0], p[0]); atomicAdd(&acc[1], p[1]); atomicAdd(&acc[2], p[2]);
    atomicAdd(&acc[3], p[3]); atomicAdd(&acc[4], p[4]);
  }
}

__global__ __launch_bounds__(BLOCK) void point_kernel(
    const float* __restrict__ pred, const float* __restrict__ grad,
    float* __restrict__ acc, int M) {
  int i = blockIdx.x * blockDim.x + threadIdx.x;
  float p[2] = {0.f, 0.f};
  if (i < M) {
    p[0] = __expf(-100.0f * fabsf(pred[i]));
    float gx = grad[3 * i], gy = grad[3 * i + 1], gz = grad[3 * i + 2];
    p[1] = fabsf(sqrtf(gx * gx + gy * gy + gz * gz) - 1.0f);
  }
  block_reduce<2>(p);
  if (threadIdx.x == 0) {
    atomicAdd(&acc[5], p[0]); atomicAdd(&acc[1], p[1]);
  }
}

__global__ void finalize_acc(const float* __restrict__ acc, float* __restrict__ out,
                             int N, int M) {
  if (threadIdx.x == 0 && blockIdx.x == 0) {
    float sdf = acc[0] / (float)N;
    float eik = acc[1] / (float)(N + M);
    float morse = 0.5f * acc[2] / (3.0f * (float)N);
    float th = 0.5f * acc[3] / (3.0f * (float)N);
    float nb = acc[4] / ((float)N * (float)KVAL);
    float inter = acc[5] / (float)M;
    float loss = 7000.0f * sdf + 600.0f * inter + 50.0f * eik + 3.0f * morse +
                 10.0f * th + 30.0f * nb;
    out[0] = loss; out[1] = sdf; out[2] = inter; out[3] = eik;
    out[4] = morse; out[5] = th; out[6] = nb;
  }
}

extern "C" void kernel_launch(void* const* d_in, const int* in_sizes, int n_in,
                              void* d_out, int out_size, void* d_ws, size_t ws_size,
                              hipStream_t stream) {
  const float* mp    = (const float*)d_in[0];
  const float* npred = (const float*)d_in[1];
  const float* grad  = (const float*)d_in[2];
  const float* ngrad = (const float*)d_in[3];
  const float* H     = (const float*)d_in[4];
  const float* ngt   = (const float*)d_in[5];
  const float* theta = (const float*)d_in[6];
  const float* u     = (const float*)d_in[7];
  const float* v     = (const float*)d_in[8];
  const float* rot   = (const float*)d_in[9];
  const int*   nbr   = (const int*)d_in[10];
  float* out = (float*)d_out;

  int N = in_sizes[0];
  int M = in_sizes[1];
  int mx = (N > M) ? N : M;
  int ngroups = (mx + 3) / 4;
  int nb1a = (ngroups + BLOCK - 1) / BLOCK;
  int nbN = (N + BLOCK - 1) / BLOCK;

  size_t off_vavb = 256;
  size_t off_pq = off_vavb + (size_t)N * 16;
  size_t off_p1 = off_pq + (size_t)N * 48;
  size_t off_p2 = off_p1 + (size_t)5 * nb1a * 4;
  size_t need = off_p2 + (size_t)nbN * 4;

  if (ws_size >= need) {
    u4v* vavb    = (u4v*)((char*)d_ws + off_vavb);
    u4v* pq      = (u4v*)((char*)d_ws + off_pq);
    float* part1 = (float*)((char*)d_ws + off_p1);
    float* part2 = (float*)((char*)d_ws + off_p2);
    pass1a_kernel<<<nb1a, BLOCK, 0, stream>>>(
        theta, u, v, vavb, N, npred, ngrad, mp, grad, H, ngt, part1, nb1a, M);
    pass1b_kernel<<<nbN, BLOCK, 0, stream>>>(rot, vavb, pq, N);
    pass2_kernel<<<nbN, BLOCK, 0, stream>>>(
        vavb, pq, (const i4*)nbr, part2, N);
    finalize_fast<<<1, BLOCK, 0, stream>>>(part1, nb1a, part2, nbN, out, N, M);
  } else {
    float* acc = (float*)d_ws;
    (void)hipMemsetAsync(acc, 0, 6 * sizeof(float), stream);
    vertex_kernel<<<(N + BLOCK - 1) / BLOCK, BLOCK, 0, stream>>>(
        mp, grad, H, ngt, theta, u, v, rot, nbr, acc, N);
    point_kernel<<<(M + BLOCK - 1) / BLOCK, BLOCK, 0, stream>>>(npred, ngrad, acc, M);
    finalize_acc<<<1, 64, 0, stream>>>(acc, out, N, M);
  }
}

// Round 9
// 61.443 us; speedup vs baseline: 1.7666x; 1.7666x over previous
//
#include <hip/hip_runtime.h>
#include <math.h>

static constexpr int BLOCK = 256;
static constexpr int WAVES = BLOCK / 64;
static constexpr int KVAL = 4;
static constexpr int TILE = 512;  // vertices per S1 block

typedef float f4 __attribute__((ext_vector_type(4)));
typedef int i4 __attribute__((ext_vector_type(4)));
typedef unsigned int u4v __attribute__((ext_vector_type(4)));
union VV { u4v u4; _Float16 h[8]; };
union PQ { u4v u[3]; _Float16 h[24]; };

__device__ __forceinline__ void norm3(float x, float y, float z,
                                      float& ox, float& oy, float& oz) {
  float inv = 1.0f / (sqrtf(x * x + y * y + z * z) + 1e-12f);
  ox = x * inv; oy = y * inv; oz = z * inv;
}

template <int NV>
__device__ __forceinline__ void block_reduce(float (&p)[NV]) {
#pragma unroll
  for (int off = 32; off > 0; off >>= 1)
#pragma unroll
    for (int q = 0; q < NV; ++q) p[q] += __shfl_down(p[q], off, 64);
  __shared__ float sm[WAVES][NV];
  int wave = threadIdx.x >> 6, lane = threadIdx.x & 63;
  if (lane == 0)
#pragma unroll
    for (int q = 0; q < NV; ++q) sm[wave][q] = p[q];
  __syncthreads();
  if (threadIdx.x == 0) {
#pragma unroll
    for (int q = 0; q < NV; ++q) {
      float t = 0.f;
#pragma unroll
      for (int w = 1; w < WAVES; ++w) t += sm[w][q];
      p[q] += t;
    }
  }
}

// coalesced global->LDS copy: nf floats, dst 16B-aligned, src 16B-aligned
__device__ __forceinline__ void stage_f(float* __restrict__ dst,
                                        const float* __restrict__ src, int nf) {
  int t = threadIdx.x;
  int nf4 = nf >> 2;
  const f4* s4 = (const f4*)src;
  f4* d4 = (f4*)dst;
  for (int i = t; i < nf4; i += BLOCK) d4[i] = s4[i];
  int rem = nf & 3;
  if (t < rem) dst[nf4 * 4 + t] = src[nf4 * 4 + t];
}

// ---- S1: all streaming terms, LDS-staged records, tile=512 -----------------
__global__ __launch_bounds__(BLOCK) void s1_kernel(
    const float* __restrict__ theta, const float* __restrict__ u,
    const float* __restrict__ v, u4v* __restrict__ vavb,
    u4v* __restrict__ pq0, u4v* __restrict__ pq1, u4v* __restrict__ pq2, int N,
    const float* __restrict__ pred, const float* __restrict__ pgrad,
    const float* __restrict__ mp, const float* __restrict__ grad,
    const float* __restrict__ H, const float* __restrict__ ngt,
    const float* __restrict__ rot,
    float* __restrict__ part1, int nb1, int M) {
  __shared__ float B[9216];  // 36 KB
  int t = threadIdx.x;
  long base = (long)blockIdx.x * TILE;
  float p[5] = {0.f, 0.f, 0.f, 0.f, 0.f};  // sdf, eik, morse, halign, inter

  int cntM = 0, cntN = 0;
  if (base < M) { long c = (long)M - base; cntM = c > TILE ? TILE : (int)c; }
  if (base < N) { long c = (long)N - base; cntN = c > TILE ? TILE : (int)c; }

  // ---- phase A: pgrad | grad | ngt staged; point+vertex eikonal, inter, sdf
  if (cntM > 0) stage_f(B, pgrad + 3 * base, 3 * cntM);
  if (cntN > 0) {
    stage_f(B + 1536, grad + 3 * base, 3 * cntN);
    stage_f(B + 3072, ngt + 3 * base, 3 * cntN);
  }
  __syncthreads();
  float ngt_r[2][3];
#pragma unroll
  for (int w = 0; w < 2; ++w) {
    int k = t + 256 * w;
    long i = base + k;
    if (k < cntM) {
      float gx = B[3 * k], gy = B[3 * k + 1], gz = B[3 * k + 2];
      p[1] += fabsf(sqrtf(gx * gx + gy * gy + gz * gz) - 1.0f);
      p[4] += __expf(-100.0f * fabsf(pred[i]));
    }
    if (k < cntN) {
      float gx = B[1536 + 3 * k], gy = B[1536 + 3 * k + 1], gz = B[1536 + 3 * k + 2];
      p[1] += fabsf(sqrtf(gx * gx + gy * gy + gz * gz) - 1.0f);
      p[0] += fabsf(mp[i]);
      ngt_r[w][0] = B[3072 + 3 * k];
      ngt_r[w][1] = B[3072 + 3 * k + 1];
      ngt_r[w][2] = B[3072 + 3 * k + 2];
    }
  }
  __syncthreads();

  // ---- phase B: u | v staged; crossfield, write vavb
  if (cntN > 0) {
    stage_f(B, u + 3 * base, 3 * cntN);
    stage_f(B + 1536, v + 3 * base, 3 * cntN);
  }
  __syncthreads();
  float va_r[2][3], vb_r[2][3];
#pragma unroll
  for (int w = 0; w < 2; ++w) {
    int k = t + 256 * w;
    long i = base + k;
    if (k < cntN) {
      float s, c;
      __sincosf(theta[i], &s, &c);
      float ux = B[3 * k], uy = B[3 * k + 1], uz = B[3 * k + 2];
      float vx = B[1536 + 3 * k], vy = B[1536 + 3 * k + 1], vz = B[1536 + 3 * k + 2];
      norm3(ux * c + vx * s, uy * c + vy * s, uz * c + vz * s,
            va_r[w][0], va_r[w][1], va_r[w][2]);
      norm3(vx * c - ux * s, vy * c - uy * s, vz * c - uz * s,
            vb_r[w][0], vb_r[w][1], vb_r[w][2]);
      VV o;
      o.h[0] = (_Float16)va_r[w][0]; o.h[1] = (_Float16)va_r[w][1];
      o.h[2] = (_Float16)va_r[w][2];
      o.h[3] = (_Float16)vb_r[w][0]; o.h[4] = (_Float16)vb_r[w][1];
      o.h[5] = (_Float16)vb_r[w][2];
      o.h[6] = (_Float16)0.f; o.h[7] = (_Float16)0.f;
      vavb[i] = o.u4;
    }
  }
  __syncthreads();

  // ---- phase C: H staged; morse + hessian alignment
  if (cntN > 0) stage_f(B, H + 9 * base, 9 * cntN);
  __syncthreads();
#pragma unroll
  for (int w = 0; w < 2; ++w) {
    int k = t + 256 * w;
    if (k < cntN) {
      float h[9];
#pragma unroll
      for (int q = 0; q < 9; ++q) h[q] = B[9 * k + q];
      float n0 = ngt_r[w][0], n1 = ngt_r[w][1], n2 = ngt_r[w][2];
      p[2] += fabsf(n0 * h[0] + n1 * h[3] + n2 * h[6]) +
              fabsf(n0 * h[1] + n1 * h[4] + n2 * h[7]) +
              fabsf(n0 * h[2] + n1 * h[5] + n2 * h[8]);
      const float* va = va_r[w];
      const float* vb = vb_r[w];
      float a0 = va[0] * h[0] + va[1] * h[3] + va[2] * h[6];
      float a1 = va[0] * h[1] + va[1] * h[4] + va[2] * h[7];
      float a2 = va[0] * h[2] + va[1] * h[5] + va[2] * h[8];
      float b0 = vb[0] * h[0] + vb[1] * h[3] + vb[2] * h[6];
      float b1 = vb[0] * h[1] + vb[1] * h[4] + vb[2] * h[7];
      float b2 = vb[0] * h[2] + vb[1] * h[5] + vb[2] * h[8];
      p[3] += fabsf(a1 * va[2] - a2 * va[1]) + fabsf(a2 * va[0] - a0 * va[2]) +
              fabsf(a0 * va[1] - a1 * va[0]) + fabsf(b1 * vb[2] - b2 * vb[1]) +
              fabsf(b2 * vb[0] - b0 * vb[2]) + fabsf(b0 * vb[1] - b1 * vb[0]);
    }
  }
  __syncthreads();

  // ---- phase D: rot staged in 2 sub-tiles of 256; pq = R^T va | R^T vb -----
#pragma unroll
  for (int sp = 0; sp < 2; ++sp) {
    int cnt = cntN - 256 * sp;           // vertices in this sub-tile
    if (cnt > 256) cnt = 256;
    long sb = base + 256 * sp;
    if (cnt > 0) stage_f(B, rot + 36 * sb, 36 * cnt);
    __syncthreads();
    if (t < cnt) {
      long i = sb + t;
      const f4* rr = (const f4*)(B + 36 * t);
      float r[36];
#pragma unroll
      for (int q = 0; q < 9; ++q) {
        f4 x = rr[q];
        r[4 * q] = x.x; r[4 * q + 1] = x.y; r[4 * q + 2] = x.z; r[4 * q + 3] = x.w;
      }
      const float* va = va_r[sp];
      const float* vb = vb_r[sp];
      PQ o;
#pragma unroll
      for (int k = 0; k < KVAL; ++k) {
        const float* R = r + 9 * k;
#pragma unroll
        for (int j = 0; j < 3; ++j) {
          float pa = R[j] * va[0] + R[3 + j] * va[1] + R[6 + j] * va[2];
          float pb = R[j] * vb[0] + R[3 + j] * vb[1] + R[6 + j] * vb[2];
          o.h[6 * k + j] = (_Float16)pa;
          o.h[6 * k + 3 + j] = (_Float16)pb;
        }
      }
      pq0[i] = o.u[0]; pq1[i] = o.u[1]; pq2[i] = o.u[2];
    }
    __syncthreads();
  }

  block_reduce<5>(p);
  if (t == 0) {
#pragma unroll
    for (int q = 0; q < 5; ++q) part1[q * nb1 + blockIdx.x] = p[q];
  }
}

// ---- S3: neighbor consistency gather ---------------------------------------
__global__ __launch_bounds__(BLOCK) void s3_kernel(
    const u4v* __restrict__ vavb, const u4v* __restrict__ pq0,
    const u4v* __restrict__ pq1, const u4v* __restrict__ pq2,
    const i4* __restrict__ nbr, float* __restrict__ part2, int N) {
  int n = blockIdx.x * BLOCK + threadIdx.x;
  float p[1] = {0.f};
  if (n < N) {
    i4 jj = nbr[n];
    int js[4] = {jj.x, jj.y, jj.z, jj.w};
    VV wn[4];
#pragma unroll
    for (int k = 0; k < KVAL; ++k) wn[k].u4 = vavb[js[k]];
    PQ o;
    o.u[0] = pq0[n]; o.u[1] = pq1[n]; o.u[2] = pq2[n];
    float nsum = 0.f;
#pragma unroll
    for (int k = 0; k < KVAL; ++k) {
      float pa0 = (float)o.h[6 * k],     pa1 = (float)o.h[6 * k + 1],
            pa2 = (float)o.h[6 * k + 2];
      float pb0 = (float)o.h[6 * k + 3], pb1 = (float)o.h[6 * k + 4],
            pb2 = (float)o.h[6 * k + 5];
      float aj0 = (float)wn[k].h[0], aj1 = (float)wn[k].h[1], aj2 = (float)wn[k].h[2];
      float bj0 = (float)wn[k].h[3], bj1 = (float)wn[k].h[4], bj2 = (float)wn[k].h[5];
      nsum += fabsf(pa0 * aj0 + pa1 * aj1 + pa2 * aj2) +
              fabsf(pa0 * bj0 + pa1 * bj1 + pa2 * bj2) +
              fabsf(pb0 * aj0 + pb1 * aj1 + pb2 * aj2) +
              fabsf(pb0 * bj0 + pb1 * bj1 + pb2 * bj2) - 2.0f;
    }
    p[0] = nsum;
  }
  block_reduce<1>(p);
  if (threadIdx.x == 0) part2[blockIdx.x] = p[0];
}

// ---- finalize ---------------------------------------------------------------
__global__ __launch_bounds__(BLOCK) void finalize_fast(
    const float* __restrict__ part1, int nb1, const float* __restrict__ part2,
    int nb2, float* __restrict__ out, int N, int M) {
  float s[6] = {0.f, 0.f, 0.f, 0.f, 0.f, 0.f};
  for (int b = threadIdx.x; b < nb1; b += BLOCK) {
#pragma unroll
    for (int q = 0; q < 5; ++q) s[q] += part1[q * nb1 + b];
  }
  for (int b = threadIdx.x; b < nb2; b += BLOCK) s[5] += part2[b];
  block_reduce<6>(s);
  if (threadIdx.x == 0) {
    float sdf = s[0] / (float)N;
    float eik = s[1] / (float)(N + M);
    float morse = 0.5f * s[2] / (3.0f * (float)N);
    float th = 0.5f * s[3] / (3.0f * (float)N);
    float inter = s[4] / (float)M;
    float nb = s[5] / ((float)N * (float)KVAL);
    float loss = 7000.0f * sdf + 600.0f * inter + 50.0f * eik + 3.0f * morse +
                 10.0f * th + 30.0f * nb;
    out[0] = loss; out[1] = sdf; out[2] = inter; out[3] = eik;
    out[4] = morse; out[5] = th; out[6] = nb;
  }
}

// ---------------- fallback path (atomics, no ws tables) ---------------------
__device__ __forceinline__ void crossfield(const float* __restrict__ u,
                                           const float* __restrict__ v,
                                           const float* __restrict__ theta,
                                           int n, float va[3], float vb[3]) {
  float s, c;
  __sincosf(theta[n], &s, &c);
  float ux = u[3 * n], uy = u[3 * n + 1], uz = u[3 * n + 2];
  float vx = v[3 * n], vy = v[3 * n + 1], vz = v[3 * n + 2];
  norm3(ux * c + vx * s, uy * c + vy * s, uz * c + vz * s, va[0], va[1], va[2]);
  norm3(vx * c - ux * s, vy * c - uy * s, vz * c - uz * s, vb[0], vb[1], vb[2]);
}

__global__ __launch_bounds__(BLOCK) void vertex_kernel(
    const float* __restrict__ mp, const float* __restrict__ grad,
    const float* __restrict__ H, const float* __restrict__ ngt,
    const float* __restrict__ theta, const float* __restrict__ u,
    const float* __restrict__ v, const float* __restrict__ rot,
    const int* __restrict__ nbr, float* __restrict__ acc, int N) {
  int n = blockIdx.x * blockDim.x + threadIdx.x;
  float p[5] = {0.f, 0.f, 0.f, 0.f, 0.f};
  if (n < N) {
    float hh[9];
#pragma unroll
    for (int i = 0; i < 9; ++i) hh[i] = H[9 * (size_t)n + i];
    p[0] = fabsf(mp[n]);
    float gx = grad[3 * n], gy = grad[3 * n + 1], gz = grad[3 * n + 2];
    p[1] = fabsf(sqrtf(gx * gx + gy * gy + gz * gz) - 1.0f);
    float n0 = ngt[3 * n], n1 = ngt[3 * n + 1], n2 = ngt[3 * n + 2];
    p[2] = fabsf(n0 * hh[0] + n1 * hh[3] + n2 * hh[6]) +
           fabsf(n0 * hh[1] + n1 * hh[4] + n2 * hh[7]) +
           fabsf(n0 * hh[2] + n1 * hh[5] + n2 * hh[8]);
    float va[3], vb[3];
    crossfield(u, v, theta, n, va, vb);
    {
      float a0 = va[0] * hh[0] + va[1] * hh[3] + va[2] * hh[6];
      float a1 = va[0] * hh[1] + va[1] * hh[4] + va[2] * hh[7];
      float a2 = va[0] * hh[2] + va[1] * hh[5] + va[2] * hh[8];
      float b0 = vb[0] * hh[0] + vb[1] * hh[3] + vb[2] * hh[6];
      float b1 = vb[0] * hh[1] + vb[1] * hh[4] + vb[2] * hh[7];
      float b2 = vb[0] * hh[2] + vb[1] * hh[5] + vb[2] * hh[8];
      p[3] = fabsf(a1 * va[2] - a2 * va[1]) + fabsf(a2 * va[0] - a0 * va[2]) +
             fabsf(a0 * va[1] - a1 * va[0]) + fabsf(b1 * vb[2] - b2 * vb[1]) +
             fabsf(b2 * vb[0] - b0 * vb[2]) + fabsf(b0 * vb[1] - b1 * vb[0]);
    }
    float nsum = 0.f;
    const float* R = rot + (size_t)n * (KVAL * 9);
#pragma unroll
    for (int k = 0; k < KVAL; ++k) {
      int j = nbr[KVAL * (size_t)n + k];
      float vaj[3], vbj[3];
      crossfield(u, v, theta, j, vaj, vbj);
      float r0 = R[9 * k + 0], r1 = R[9 * k + 1], r2 = R[9 * k + 2];
      float r3 = R[9 * k + 3], r4 = R[9 * k + 4], r5 = R[9 * k + 5];
      float r6 = R[9 * k + 6], r7 = R[9 * k + 7], r8 = R[9 * k + 8];
      float wa0 = r0 * vaj[0] + r1 * vaj[1] + r2 * vaj[2];
      float wa1 = r3 * vaj[0] + r4 * vaj[1] + r5 * vaj[2];
      float wa2 = r6 * vaj[0] + r7 * vaj[1] + r8 * vaj[2];
      float wb0 = r0 * vbj[0] + r1 * vbj[1] + r2 * vbj[2];
      float wb1 = r3 * vbj[0] + r4 * vbj[1] + r5 * vbj[2];
      float wb2 = r6 * vbj[0] + r7 * vbj[1] + r8 * vbj[2];
      nsum += fabsf(va[0] * wa0 + va[1] * wa1 + va[2] * wa2) +
              fabsf(va[0] * wb0 + va[1] * wb1 + va[2] * wb2) +
              fabsf(vb[0] * wa0 + vb[1] * wa1 + vb[2] * wa2) +
              fabsf(vb[0] * wb0 + vb[1] * wb1 + vb[2] * wb2) - 2.0f;
    }
    p[4] = nsum;
  }
  block_reduce<5>(p);
  if (threadIdx.x == 0) {
    atomicAdd(&acc[0], p[0]); atomicAdd(&acc[1], p[1]); atomicAdd(&acc[2], p[2]);
    atomicAdd(&acc[3], p[3]); atomicAdd(&acc[4], p[4]);
  }
}

__global__ __launch_bounds__(BLOCK) void point_kernel(
    const float* __restrict__ pred, const float* __restrict__ grad,
    float* __restrict__ acc, int M) {
  int i = blockIdx.x * blockDim.x + threadIdx.x;
  float p[2] = {0.f, 0.f};
  if (i < M) {
    p[0] = __expf(-100.0f * fabsf(pred[i]));
    float gx = grad[3 * i], gy = grad[3 * i + 1], gz = grad[3 * i + 2];
    p[1] = fabsf(sqrtf(gx * gx + gy * gy + gz * gz) - 1.0f);
  }
  block_reduce<2>(p);
  if (threadIdx.x == 0) {
    atomicAdd(&acc[5], p[0]); atomicAdd(&acc[1], p[1]);
  }
}

__global__ void finalize_acc(const float* __restrict__ acc, float* __restrict__ out,
                             int N, int M) {
  if (threadIdx.x == 0 && blockIdx.x == 0) {
    float sdf = acc[0] / (float)N;
    float eik = acc[1] / (float)(N + M);
    float morse = 0.5f * acc[2] / (3.0f * (float)N);
    float th = 0.5f * acc[3] / (3.0f * (float)N);
    float nb = acc[4] / ((float)N * (float)KVAL);
    float inter = acc[5] / (float)M;
    float loss = 7000.0f * sdf + 600.0f * inter + 50.0f * eik + 3.0f * morse +
                 10.0f * th + 30.0f * nb;
    out[0] = loss; out[1] = sdf; out[2] = inter; out[3] = eik;
    out[4] = morse; out[5] = th; out[6] = nb;
  }
}

extern "C" void kernel_launch(void* const* d_in, const int* in_sizes, int n_in,
                              void* d_out, int out_size, void* d_ws, size_t ws_size,
                              hipStream_t stream) {
  const float* mp    = (const float*)d_in[0];
  const float* npred = (const float*)d_in[1];
  const float* grad  = (const float*)d_in[2];
  const float* ngrad = (const float*)d_in[3];
  const float* H     = (const float*)d_in[4];
  const float* ngt   = (const float*)d_in[5];
  const float* theta = (const float*)d_in[6];
  const float* u     = (const float*)d_in[7];
  const float* v     = (const float*)d_in[8];
  const float* rot   = (const float*)d_in[9];
  const int*   nbr   = (const int*)d_in[10];
  float* out = (float*)d_out;

  int N = in_sizes[0];
  int M = in_sizes[1];
  int mx = (N > M) ? N : M;
  int nb1 = (mx + TILE - 1) / TILE;         // S1 blocks
  int nb2 = (N + BLOCK - 1) / BLOCK;        // S3 blocks

  size_t off_vavb = 256;
  size_t off_pq0 = off_vavb + (size_t)N * 16;
  size_t off_pq1 = off_pq0 + (size_t)N * 16;
  size_t off_pq2 = off_pq1 + (size_t)N * 16;
  size_t off_p1 = off_pq2 + (size_t)N * 16;
  size_t off_p2 = off_p1 + (size_t)5 * nb1 * 4;
  size_t need = off_p2 + (size_t)nb2 * 4;

  if (ws_size >= need) {
    u4v* vavb    = (u4v*)((char*)d_ws + off_vavb);
    u4v* pq0     = (u4v*)((char*)d_ws + off_pq0);
    u4v* pq1     = (u4v*)((char*)d_ws + off_pq1);
    u4v* pq2     = (u4v*)((char*)d_ws + off_pq2);
    float* part1 = (float*)((char*)d_ws + off_p1);
    float* part2 = (float*)((char*)d_ws + off_p2);
    s1_kernel<<<nb1, BLOCK, 0, stream>>>(
        theta, u, v, vavb, pq0, pq1, pq2, N, npred, ngrad, mp, grad, H, ngt,
        rot, part1, nb1, M);
    s3_kernel<<<nb2, BLOCK, 0, stream>>>(
        vavb, pq0, pq1, pq2, (const i4*)nbr, part2, N);
    finalize_fast<<<1, BLOCK, 0, stream>>>(part1, nb1, part2, nb2, out, N, M);
  } else {
    float* acc = (float*)d_ws;
    (void)hipMemsetAsync(acc, 0, 6 * sizeof(float), stream);
    vertex_kernel<<<(N + BLOCK - 1) / BLOCK, BLOCK, 0, stream>>>(
        mp, grad, H, ngt, theta, u, v, rot, nbr, acc, N);
    point_kernel<<<(M + BLOCK - 1) / BLOCK, BLOCK, 0, stream>>>(npred, ngrad, acc, M);
    finalize_acc<<<1, 64, 0, stream>>>(acc, out, N, M);
  }
}